// Round 1
// 1301.694 us; speedup vs baseline: 1.0061x; 1.0061x over previous
//
#include <hip/hip_runtime.h>

// Problem constants (fixed by the reference file)
constexpr int Bn = 4, Hn = 16, Sn = 2048, Dn = 64;
constexpr float MASK_FILL = -1e9f;

typedef __bf16 bf16x8 __attribute__((ext_vector_type(8)));
typedef __bf16 bf16x4 __attribute__((ext_vector_type(4)));
typedef float  f32x4  __attribute__((ext_vector_type(4)));
typedef int    i32x4  __attribute__((ext_vector_type(4)));

// LDS strides in elements (__bf16). Rows padded to keep 16B alignment
// (stride multiple of 8 elems) while breaking power-of-2 bank strides.
#define KSTRIDE 72    // K and Q/S-scratch tiles: [128][72]
#define VSTRIDE 136   // V-transposed tile:      [64][136]

// Raw barrier: waits only LDS ops, NOT vmcnt — keeps the 1.07GB of attn
// stores in flight across tiles (the __syncthreads() vmcnt(0) drain was
// serializing store retirement with compute). Single asm block so no memory
// op can be scheduled between the wait and the barrier.
#define BARRIER_LGKM() asm volatile("s_waitcnt lgkmcnt(0)\n\ts_barrier" ::: "memory")

// Fused attention (no softmax): per block computes a 128-row Q stripe of one
// (b,h). Both MFMAs are OPERAND-SWAPPED (mfma(K,Q), mfma(V,S)) so the C/D
// layout (row = m-operand idx, col = lane&15) puts 4 CONSECUTIVE memory
// columns in each lane -> all global stores are f32x4.
__global__ __launch_bounds__(256, 2) void attn_fused(
    const float* __restrict__ qg, const float* __restrict__ kg,
    const float* __restrict__ vg, const int* __restrict__ maskg,
    float* __restrict__ outg, float* __restrict__ attng)
{
  __shared__ __align__(16) __bf16 lds_k [128 * KSTRIDE];
  __shared__ __align__(16) __bf16 lds_vt[ 64 * VSTRIDE];
  __shared__ __align__(16) __bf16 lds_qs[128 * KSTRIDE];  // Q tile, then per-wave S scratch
  __shared__ __align__(16) int    lds_m [Sn];             // full mask row for this b

  // Bijective XCD swizzle (1024 wg, 8 XCDs, 128 per chunk): each XCD ends up
  // working ~4 concurrent (b,h) -> K/V working set ~4MB fits its private L2.
  const int fid  = blockIdx.y * gridDim.x + blockIdx.x;
  const int nf   = ((fid & 7) << 7) | (fid >> 3);
  const int qt   = nf & 15;           // 0..15 query tile
  const int bh   = nf >> 4;           // 0..63 (b*16+h)
  const int b    = bh >> 4;
  const int tid  = threadIdx.x;
  const int wave = tid >> 6;
  const int lane = tid & 63;
  const int quad = lane >> 4;
  const int l16  = lane & 15;

  const size_t hbase = (size_t)bh * Sn * Dn;
  const float* qp = qg + hbase + (size_t)qt * 128 * Dn;
  float* attnp = attng + (size_t)bh * Sn * Sn + (size_t)qt * 128 * (size_t)Sn;

  const int r0 = tid >> 4;          // 0..15
  const int c  = (tid & 15) << 2;   // 0..60

  // ---- stage full mask row (once per block) ----
  {
    const int* mp = maskg + b * Sn;
    *(i32x4*)&lds_m[tid * 8]     = *(const i32x4*)(mp + tid * 8);
    *(i32x4*)&lds_m[tid * 8 + 4] = *(const i32x4*)(mp + tid * 8 + 4);
  }

  // ---- stage Q tile (pre-scaled by 1/temperature = 0.125, exact pow2) ----
#pragma unroll
  for (int i = 0; i < 8; ++i) {
    const int r = r0 + (i << 4);
    f32x4 val = __builtin_nontemporal_load((const f32x4*)(qp + r * Dn + c));
    bf16x4 pk;
    pk.x = (__bf16)(val.x * 0.125f);
    pk.y = (__bf16)(val.y * 0.125f);
    pk.z = (__bf16)(val.z * 0.125f);
    pk.w = (__bf16)(val.w * 0.125f);
    *(bf16x4*)&lds_qs[r * KSTRIDE + c] = pk;
  }

  // ---- prefetch K/V tile 0 into registers (T14: issue early, write late) ----
  f32x4 kpre[8], vpre[8];
  const float* kbase = kg + hbase;
  const float* vbase = vg + hbase;
#pragma unroll
  for (int i = 0; i < 8; ++i) {
    const int r = r0 + (i << 4);
    kpre[i] = *(const f32x4*)(kbase + r * Dn + c);
    vpre[i] = *(const f32x4*)(vbase + r * Dn + c);
  }

  BARRIER_LGKM();

  // ---- hoist per-wave Q fragments (frag layout: [n=lane&15][k=quad*8+j]) ----
  bf16x8 qa[2][2];
#pragma unroll
  for (int qs = 0; qs < 2; ++qs)
#pragma unroll
    for (int ks = 0; ks < 2; ++ks)
      qa[qs][ks] = *(const bf16x8*)&lds_qs[(wave * 32 + qs * 16 + l16) * KSTRIDE + ks * 32 + quad * 8];

  // Per-wave private S scratch aliases this wave's own 32 rows of the Q tile.
  __bf16* sbuf = &lds_qs[wave * 32 * KSTRIDE];

  f32x4 oacc[2][4];
#pragma unroll
  for (int qs = 0; qs < 2; ++qs)
#pragma unroll
    for (int ds = 0; ds < 4; ++ds)
      oacc[qs][ds] = (f32x4){0.f, 0.f, 0.f, 0.f};

  for (int kt = 0; kt < 16; ++kt) {
    BARRIER_LGKM();   // all waves done reading previous K/V LDS tiles

    // ---- write prefetched K (row-major) and V (transposed) tiles as bf16 ----
    // (compiler emits a counted vmcnt here: the prefetch loads are older than
    //  the in-flight attn stores, so those keep streaming)
#pragma unroll
    for (int i = 0; i < 8; ++i) {
      const int r = r0 + (i << 4);
      f32x4 kv = kpre[i];
      bf16x4 pk;
      pk.x = (__bf16)kv.x; pk.y = (__bf16)kv.y;
      pk.z = (__bf16)kv.z; pk.w = (__bf16)kv.w;
      *(bf16x4*)&lds_k[r * KSTRIDE + c] = pk;
      f32x4 vv = vpre[i];
      lds_vt[(c + 0) * VSTRIDE + r] = (__bf16)vv.x;
      lds_vt[(c + 1) * VSTRIDE + r] = (__bf16)vv.y;
      lds_vt[(c + 2) * VSTRIDE + r] = (__bf16)vv.z;
      lds_vt[(c + 3) * VSTRIDE + r] = (__bf16)vv.w;
    }

    BARRIER_LGKM();   // publish K/V tile

    // ---- issue next tile's loads BEFORE this tile's stores (queue order:
    //      loads ahead of stores -> their completion is never store-blocked) ----
    if (kt < 15) {
      const float* kp = kbase + (size_t)((kt + 1) * 128) * Dn;
      const float* vp = vbase + (size_t)((kt + 1) * 128) * Dn;
#pragma unroll
      for (int i = 0; i < 8; ++i) {
        const int r = r0 + (i << 4);
        kpre[i] = *(const f32x4*)(kp + r * Dn + c);
        vpre[i] = *(const f32x4*)(vp + r * Dn + c);
      }
    }

    // ---- S = K @ Q^T (swapped): D[m = k-col][n = q-row]
    //      lane holds attn[q = qs*16+l16][k = ns*16 + quad*4 + (0..3)] ----
    f32x4 sacc[2][8];
#pragma unroll
    for (int ns = 0; ns < 8; ++ns) {
      bf16x8 ka0 = *(const bf16x8*)&lds_k[(ns * 16 + l16) * KSTRIDE +      quad * 8];
      bf16x8 ka1 = *(const bf16x8*)&lds_k[(ns * 16 + l16) * KSTRIDE + 32 + quad * 8];
#pragma unroll
      for (int qs = 0; qs < 2; ++qs) {
        f32x4 acc = (f32x4){0.f, 0.f, 0.f, 0.f};
        acc = __builtin_amdgcn_mfma_f32_16x16x32_bf16(ka0, qa[qs][0], acc, 0, 0, 0);
        acc = __builtin_amdgcn_mfma_f32_16x16x32_bf16(ka1, qa[qs][1], acc, 0, 0, 0);
        sacc[qs][ns] = acc;
      }
    }

    // ---- mask fill + vectorized f32x4 nontemporal attn stores ----
#pragma unroll
    for (int ns = 0; ns < 8; ++ns) {
      const i32x4 m4 = *(const i32x4*)&lds_m[kt * 128 + ns * 16 + quad * 4];
#pragma unroll
      for (int qs = 0; qs < 2; ++qs) {
        f32x4 sv = sacc[qs][ns];
        sv.x = m4.x ? sv.x : MASK_FILL;
        sv.y = m4.y ? sv.y : MASK_FILL;
        sv.z = m4.z ? sv.z : MASK_FILL;
        sv.w = m4.w ? sv.w : MASK_FILL;
        sacc[qs][ns] = sv;
        const int row = wave * 32 + qs * 16 + l16;
        __builtin_nontemporal_store(sv,
            (f32x4*)(attnp + (size_t)row * Sn + kt * 128 + ns * 16 + quad * 4));
      }
    }

    // ---- O += S @ V, in two 64-col halves through per-wave LDS scratch ----
#pragma unroll
    for (int half = 0; half < 2; ++half) {
#pragma unroll
      for (int ns4 = 0; ns4 < 4; ++ns4) {
        const int ns = half * 4 + ns4;
#pragma unroll
        for (int qs = 0; qs < 2; ++qs) {
          f32x4 sv = sacc[qs][ns];
          bf16x4 sb;
          sb.x = (__bf16)sv.x; sb.y = (__bf16)sv.y;
          sb.z = (__bf16)sv.z; sb.w = (__bf16)sv.w;
          *(bf16x4*)&sbuf[(qs * 16 + l16) * KSTRIDE + ns4 * 16 + quad * 4] = sb;
        }
      }
      // Same-wave DS ops execute in order; fence only stops compiler reordering.
      asm volatile("" ::: "memory");
#pragma unroll
      for (int ks = 0; ks < 2; ++ks) {
        bf16x8 sb0 = *(const bf16x8*)&sbuf[(     l16) * KSTRIDE + ks * 32 + quad * 8];
        bf16x8 sb1 = *(const bf16x8*)&sbuf[(16 + l16) * KSTRIDE + ks * 32 + quad * 8];
#pragma unroll
        for (int ds = 0; ds < 4; ++ds) {
          bf16x8 va = *(const bf16x8*)&lds_vt[(ds * 16 + l16) * VSTRIDE + half * 64 + ks * 32 + quad * 8];
          // swapped: D[m = d-offset][n = q-row] -> epilogue stores are f32x4
          oacc[0][ds] = __builtin_amdgcn_mfma_f32_16x16x32_bf16(va, sb0, oacc[0][ds], 0, 0, 0);
          oacc[1][ds] = __builtin_amdgcn_mfma_f32_16x16x32_bf16(va, sb1, oacc[1][ds], 0, 0, 0);
        }
      }
      asm volatile("" ::: "memory");  // keep next half's sbuf writes after these reads
    }
  }

  // ---- epilogue: vectorized O stores (lane holds 4 consecutive d) ----
  float* op = outg + hbase + (size_t)qt * 128 * Dn;
#pragma unroll
  for (int qs = 0; qs < 2; ++qs)
#pragma unroll
    for (int ds = 0; ds < 4; ++ds) {
      const int row = wave * 32 + qs * 16 + l16;
      __builtin_nontemporal_store(oacc[qs][ds],
          (f32x4*)(op + (size_t)row * Dn + ds * 16 + quad * 4));
    }
}

extern "C" void kernel_launch(void* const* d_in, const int* in_sizes, int n_in,
                              void* d_out, int out_size, void* d_ws, size_t ws_size,
                              hipStream_t stream) {
  const float* q    = (const float*)d_in[0];
  const float* k    = (const float*)d_in[1];
  const float* v    = (const float*)d_in[2];
  const int*   mask = (const int*)d_in[3];
  float* out  = (float*)d_out;
  float* attn = out + (size_t)Bn * Hn * Sn * Dn;   // outputs concatenated: (output, attn)

  dim3 grid(Sn / 128, Bn * Hn);
  attn_fused<<<grid, 256, 0, stream>>>(q, k, v, mask, out, attn);
}

// Round 4
// 1297.834 us; speedup vs baseline: 1.0091x; 1.0030x over previous
//
#include <hip/hip_runtime.h>

// Problem constants (fixed by the reference file)
constexpr int Bn = 4, Hn = 16, Sn = 2048, Dn = 64;
constexpr float MASK_FILL = -1e9f;

typedef __bf16 bf16x8 __attribute__((ext_vector_type(8)));
typedef __bf16 bf16x4 __attribute__((ext_vector_type(4)));
typedef float  f32x4  __attribute__((ext_vector_type(4)));
typedef int    i32x4  __attribute__((ext_vector_type(4)));

// LDS strides in elements (__bf16).
#define KSTRIDE 72    // K and Q/S-scratch tiles: [128 rows][64+pad]
#define VSTRIDE 136   // V-transposed tile: [64 d-rows][128 k + pad]  (k is the
                      // ROW LENGTH here — must be >=128; 72 was round-3's bug)

// Raw barrier: waits only LDS ops, NOT vmcnt — attn stores stay in flight.
#define BARRIER_LGKM() asm volatile("s_waitcnt lgkmcnt(0)\n\ts_barrier" ::: "memory")

// Fused attention (no softmax): per block computes a 128-row Q stripe of one
// (b,h). Both MFMAs are operand-swapped (mfma(K,Q), mfma(V,S)) so each lane
// holds 4 consecutive attn columns -> all global stores are f32x4.
// V is transposed IN REGISTERS (each thread loads 8 consecutive k-rows of 4
// d-cols, repacks to 4x bf16x8 along k) and staged with ds_write_b128 into the
// [d][k] tile: replaces the 32x scalar ds_write_b16 @~16-way-conflict path
// while keeping the round-1-verified bf16x8 PV read pattern (VSTRIDE=136).
__global__ __launch_bounds__(256, 2) void attn_fused(
    const float* __restrict__ qg, const float* __restrict__ kg,
    const float* __restrict__ vg, const int* __restrict__ maskg,
    float* __restrict__ outg, float* __restrict__ attng)
{
  __shared__ __align__(16) __bf16 lds_k [128 * KSTRIDE];
  __shared__ __align__(16) __bf16 lds_vt[ 64 * VSTRIDE];
  __shared__ __align__(16) __bf16 lds_qs[128 * KSTRIDE];  // Q tile, then per-wave S scratch
  __shared__ __align__(16) int    lds_m [Sn];             // full mask row for this b

  // Bijective XCD swizzle (1024 wg, 8 XCDs): each XCD works ~4 concurrent
  // (b,h) -> K/V working set ~4MB fits its private L2.
  const int fid  = blockIdx.y * gridDim.x + blockIdx.x;
  const int nf   = ((fid & 7) << 7) | (fid >> 3);
  const int qt   = nf & 15;           // 0..15 query tile
  const int bh   = nf >> 4;           // 0..63 (b*16+h)
  const int b    = bh >> 4;
  const int tid  = threadIdx.x;
  const int wave = tid >> 6;
  const int lane = tid & 63;
  const int quad = lane >> 4;
  const int l16  = lane & 15;

  const size_t hbase = (size_t)bh * Sn * Dn;
  const float* qp = qg + hbase + (size_t)qt * 128 * Dn;
  float* attnp = attng + (size_t)bh * Sn * Sn + (size_t)qt * 128 * (size_t)Sn;

  const int r0 = tid >> 4;          // 0..15
  const int c  = (tid & 15) << 2;   // 0..60

  // ---- stage full mask row (once per block) ----
  {
    const int* mp = maskg + b * Sn;
    *(i32x4*)&lds_m[tid * 8]     = *(const i32x4*)(mp + tid * 8);
    *(i32x4*)&lds_m[tid * 8 + 4] = *(const i32x4*)(mp + tid * 8 + 4);
  }

  // ---- stage Q tile (pre-scaled by 1/temperature = 0.125, exact pow2) ----
#pragma unroll
  for (int i = 0; i < 8; ++i) {
    const int r = r0 + (i << 4);
    f32x4 val = __builtin_nontemporal_load((const f32x4*)(qp + r * Dn + c));
    bf16x4 pk;
    pk.x = (__bf16)(val.x * 0.125f);
    pk.y = (__bf16)(val.y * 0.125f);
    pk.z = (__bf16)(val.z * 0.125f);
    pk.w = (__bf16)(val.w * 0.125f);
    *(bf16x4*)&lds_qs[r * KSTRIDE + c] = pk;
  }

  // ---- prefetch K/V tile 0 into registers (issue early, write late) ----
  // K rows: r0 + 16i (row-major staging). V rows: r0*8 + i — each thread owns
  // 8 CONSECUTIVE k so the LDS transpose write can be a single b128 per d-col.
  f32x4 kpre[8], vpre[8];
  const float* kbase = kg + hbase;
  const float* vbase = vg + hbase;
#pragma unroll
  for (int i = 0; i < 8; ++i) {
    kpre[i] = *(const f32x4*)(kbase + (r0 + (i << 4)) * Dn + c);
    vpre[i] = *(const f32x4*)(vbase + (r0 * 8 + i) * Dn + c);
  }

  BARRIER_LGKM();

  // ---- hoist per-wave Q fragments (frag layout: [n=lane&15][k=quad*8+j]) ----
  bf16x8 qa[2][2];
#pragma unroll
  for (int qs = 0; qs < 2; ++qs)
#pragma unroll
    for (int ks = 0; ks < 2; ++ks)
      qa[qs][ks] = *(const bf16x8*)&lds_qs[(wave * 32 + qs * 16 + l16) * KSTRIDE + ks * 32 + quad * 8];

  // Per-wave private S scratch aliases this wave's own 32 rows of the Q tile.
  __bf16* sbuf = &lds_qs[wave * 32 * KSTRIDE];

  f32x4 oacc[2][4];
#pragma unroll
  for (int qs = 0; qs < 2; ++qs)
#pragma unroll
    for (int ds = 0; ds < 4; ++ds)
      oacc[qs][ds] = (f32x4){0.f, 0.f, 0.f, 0.f};

  for (int kt = 0; kt < 16; ++kt) {
    BARRIER_LGKM();   // all waves done reading previous K/V LDS tiles

    // ---- write prefetched K (row-major) and V (reg-transposed) as bf16 ----
#pragma unroll
    for (int i = 0; i < 8; ++i) {
      const int r = r0 + (i << 4);
      f32x4 kv = kpre[i];
      bf16x4 pk;
      pk.x = (__bf16)kv.x; pk.y = (__bf16)kv.y;
      pk.z = (__bf16)kv.z; pk.w = (__bf16)kv.w;
      *(bf16x4*)&lds_k[r * KSTRIDE + c] = pk;
    }
#pragma unroll
    for (int j = 0; j < 4; ++j) {       // d-col = c + j
      bf16x8 t;
#pragma unroll
      for (int i = 0; i < 8; ++i)       // k-row = r0*8 + i (consecutive)
        t[i] = (__bf16)vpre[i][j];
      *(bf16x8*)&lds_vt[(c + j) * VSTRIDE + r0 * 8] = t;
    }

    BARRIER_LGKM();   // publish K/V tile

    // ---- issue next tile's loads BEFORE this tile's stores (FIFO vmcnt:
    //      loads older than stores -> LDS-write wait never drains stores) ----
    if (kt < 15) {
      const float* kp = kbase + (size_t)((kt + 1) * 128) * Dn;
      const float* vp = vbase + (size_t)((kt + 1) * 128) * Dn;
#pragma unroll
      for (int i = 0; i < 8; ++i) {
        kpre[i] = *(const f32x4*)(kp + (r0 + (i << 4)) * Dn + c);
        vpre[i] = *(const f32x4*)(vp + (r0 * 8 + i) * Dn + c);
      }
    }

    // ---- S = K @ Q^T (swapped) fused with mask-fill + f32x4 attn stores.
    //      Plain (cacheable) stores: the wave writes both 64B halves of each
    //      128B sector close together -> L2 merges to full-line writebacks. ----
    f32x4 sacc[2][8];
#pragma unroll
    for (int ns = 0; ns < 8; ++ns) {
      bf16x8 ka0 = *(const bf16x8*)&lds_k[(ns * 16 + l16) * KSTRIDE +      quad * 8];
      bf16x8 ka1 = *(const bf16x8*)&lds_k[(ns * 16 + l16) * KSTRIDE + 32 + quad * 8];
      const i32x4 m4 = *(const i32x4*)&lds_m[kt * 128 + ns * 16 + quad * 4];
#pragma unroll
      for (int qs = 0; qs < 2; ++qs) {
        f32x4 acc = (f32x4){0.f, 0.f, 0.f, 0.f};
        acc = __builtin_amdgcn_mfma_f32_16x16x32_bf16(ka0, qa[qs][0], acc, 0, 0, 0);
        acc = __builtin_amdgcn_mfma_f32_16x16x32_bf16(ka1, qa[qs][1], acc, 0, 0, 0);
        acc.x = m4.x ? acc.x : MASK_FILL;
        acc.y = m4.y ? acc.y : MASK_FILL;
        acc.z = m4.z ? acc.z : MASK_FILL;
        acc.w = m4.w ? acc.w : MASK_FILL;
        sacc[qs][ns] = acc;
        const int row = wave * 32 + qs * 16 + l16;
        *(f32x4*)(attnp + (size_t)row * Sn + kt * 128 + ns * 16 + quad * 4) = acc;
      }
    }

    // ---- O += S @ V, two 64-col halves; S through per-wave LDS scratch,
    //      V via bf16x8 reads from the transposed tile (round-1-verified) ----
#pragma unroll
    for (int half = 0; half < 2; ++half) {
#pragma unroll
      for (int ns4 = 0; ns4 < 4; ++ns4) {
        const int ns = half * 4 + ns4;
#pragma unroll
        for (int qs = 0; qs < 2; ++qs) {
          f32x4 sv = sacc[qs][ns];
          bf16x4 sb;
          sb.x = (__bf16)sv.x; sb.y = (__bf16)sv.y;
          sb.z = (__bf16)sv.z; sb.w = (__bf16)sv.w;
          *(bf16x4*)&sbuf[(qs * 16 + l16) * KSTRIDE + ns4 * 16 + quad * 4] = sb;
        }
      }
      asm volatile("" ::: "memory");
#pragma unroll
      for (int ks = 0; ks < 2; ++ks) {
        bf16x8 sb0 = *(const bf16x8*)&sbuf[(     l16) * KSTRIDE + ks * 32 + quad * 8];
        bf16x8 sb1 = *(const bf16x8*)&sbuf[(16 + l16) * KSTRIDE + ks * 32 + quad * 8];
#pragma unroll
        for (int ds = 0; ds < 4; ++ds) {
          bf16x8 va = *(const bf16x8*)&lds_vt[(ds * 16 + l16) * VSTRIDE + half * 64 + ks * 32 + quad * 8];
          // swapped: D[m = d-offset][n = q-row] -> epilogue stores are f32x4
          oacc[0][ds] = __builtin_amdgcn_mfma_f32_16x16x32_bf16(va, sb0, oacc[0][ds], 0, 0, 0);
          oacc[1][ds] = __builtin_amdgcn_mfma_f32_16x16x32_bf16(va, sb1, oacc[1][ds], 0, 0, 0);
        }
      }
      asm volatile("" ::: "memory");  // keep next half's sbuf writes after these reads
    }
  }

  // ---- epilogue: vectorized O stores (lane holds 4 consecutive d) ----
  float* op = outg + hbase + (size_t)qt * 128 * Dn;
#pragma unroll
  for (int qs = 0; qs < 2; ++qs)
#pragma unroll
    for (int ds = 0; ds < 4; ++ds) {
      const int row = wave * 32 + qs * 16 + l16;
      __builtin_nontemporal_store(oacc[qs][ds],
          (f32x4*)(op + (size_t)row * Dn + ds * 16 + quad * 4));
    }
}

extern "C" void kernel_launch(void* const* d_in, const int* in_sizes, int n_in,
                              void* d_out, int out_size, void* d_ws, size_t ws_size,
                              hipStream_t stream) {
  const float* q    = (const float*)d_in[0];
  const float* k    = (const float*)d_in[1];
  const float* v    = (const float*)d_in[2];
  const int*   mask = (const int*)d_in[3];
  float* out  = (float*)d_out;
  float* attn = out + (size_t)Bn * Hn * Sn * Dn;   // outputs concatenated: (output, attn)

  dim3 grid(Sn / 128, Bn * Hn);
  attn_fused<<<grid, 256, 0, stream>>>(q, k, v, mask, out, attn);
}

// Round 5
// 1217.518 us; speedup vs baseline: 1.0757x; 1.0660x over previous
//
#include <hip/hip_runtime.h>

// Problem constants (fixed by the reference file)
constexpr int Bn = 4, Hn = 16, Sn = 2048, Dn = 64;
constexpr float MASK_FILL = -1e9f;

typedef __bf16 bf16x8 __attribute__((ext_vector_type(8)));
typedef __bf16 bf16x4 __attribute__((ext_vector_type(4)));
typedef float  f32x4  __attribute__((ext_vector_type(4)));
typedef int    i32x4  __attribute__((ext_vector_type(4)));

// LDS strides in elements (__bf16).
#define KSTRIDE 72    // K and Q/S-scratch tiles: [128 rows][64+pad]
#define VSTRIDE 136   // V-transposed tile: [64 d-rows][128 k + pad]

// Raw barrier: waits only LDS ops, NOT vmcnt — attn stores stay in flight.
#define BARRIER_LGKM() asm volatile("s_waitcnt lgkmcnt(0)\n\ts_barrier" ::: "memory")

// Fused attention (no softmax): per block computes a 128-row Q stripe of one
// (b,h). Both MFMAs are operand-swapped (mfma(K,Q), mfma(V,S)) so each lane
// holds 4 consecutive attn columns -> all global stores are f32x4.
//
// KT PHASE STAGGER (this round's lever): attn rows are 8KB apart, which is
// above the HBM channel-interleave bits -> a kt-iteration's stores all land
// on ~2 channel granules, and with every block iterating kt=0..15 in the same
// order the whole GPU hammers the same few DRAM channels at any instant
// (observed ~1.8 TB/s effective write BW vs 6.3 achievable). Starting each
// block at kt0 = nf&15 spreads concurrent stores across all 16 column ranges
// = all channels. kt tiles are independent (attn writes disjoint; O sum is
// reorderable within fp tolerance), so this is purely a scheduling change.
__global__ __launch_bounds__(256, 2) void attn_fused(
    const float* __restrict__ qg, const float* __restrict__ kg,
    const float* __restrict__ vg, const int* __restrict__ maskg,
    float* __restrict__ outg, float* __restrict__ attng)
{
  __shared__ __align__(16) __bf16 lds_k [128 * KSTRIDE];
  __shared__ __align__(16) __bf16 lds_vt[ 64 * VSTRIDE];
  __shared__ __align__(16) __bf16 lds_qs[128 * KSTRIDE];  // Q tile, then per-wave S scratch
  __shared__ __align__(16) int    lds_m [Sn];             // full mask row for this b

  // Bijective XCD swizzle (1024 wg, 8 XCDs): each XCD works ~4 concurrent
  // (b,h) -> K/V working set ~4MB fits its private L2.
  const int fid  = blockIdx.y * gridDim.x + blockIdx.x;
  const int nf   = ((fid & 7) << 7) | (fid >> 3);
  const int qt   = nf & 15;           // 0..15 query tile
  const int bh   = nf >> 4;           // 0..63 (b*16+h)
  const int b    = bh >> 4;
  const int tid  = threadIdx.x;
  const int wave = tid >> 6;
  const int lane = tid & 63;
  const int quad = lane >> 4;
  const int l16  = lane & 15;

  const int kt0  = nf & 15;           // per-block K-tile phase offset

  const size_t hbase = (size_t)bh * Sn * Dn;
  const float* qp = qg + hbase + (size_t)qt * 128 * Dn;
  float* attnp = attng + (size_t)bh * Sn * Sn + (size_t)qt * 128 * (size_t)Sn;

  const int r0 = tid >> 4;          // 0..15
  const int c  = (tid & 15) << 2;   // 0..60

  // ---- stage full mask row (once per block) ----
  {
    const int* mp = maskg + b * Sn;
    *(i32x4*)&lds_m[tid * 8]     = *(const i32x4*)(mp + tid * 8);
    *(i32x4*)&lds_m[tid * 8 + 4] = *(const i32x4*)(mp + tid * 8 + 4);
  }

  // ---- stage Q tile (pre-scaled by 1/temperature = 0.125, exact pow2) ----
#pragma unroll
  for (int i = 0; i < 8; ++i) {
    const int r = r0 + (i << 4);
    f32x4 val = __builtin_nontemporal_load((const f32x4*)(qp + r * Dn + c));
    bf16x4 pk;
    pk.x = (__bf16)(val.x * 0.125f);
    pk.y = (__bf16)(val.y * 0.125f);
    pk.z = (__bf16)(val.z * 0.125f);
    pk.w = (__bf16)(val.w * 0.125f);
    *(bf16x4*)&lds_qs[r * KSTRIDE + c] = pk;
  }

  // ---- prefetch K/V tile kt0 into registers (issue early, write late) ----
  // K rows: r0 + 16i (row-major staging). V rows: r0*8 + i — each thread owns
  // 8 CONSECUTIVE k so the LDS transpose write can be a single b128 per d-col.
  f32x4 kpre[8], vpre[8];
  const float* kbase = kg + hbase;
  const float* vbase = vg + hbase;
  {
    const float* kp = kbase + (size_t)(kt0 * 128) * Dn;
    const float* vp = vbase + (size_t)(kt0 * 128) * Dn;
#pragma unroll
    for (int i = 0; i < 8; ++i) {
      kpre[i] = *(const f32x4*)(kp + (r0 + (i << 4)) * Dn + c);
      vpre[i] = *(const f32x4*)(vp + (r0 * 8 + i) * Dn + c);
    }
  }

  BARRIER_LGKM();

  // ---- hoist per-wave Q fragments (frag layout: [n=lane&15][k=quad*8+j]) ----
  bf16x8 qa[2][2];
#pragma unroll
  for (int qs = 0; qs < 2; ++qs)
#pragma unroll
    for (int ks = 0; ks < 2; ++ks)
      qa[qs][ks] = *(const bf16x8*)&lds_qs[(wave * 32 + qs * 16 + l16) * KSTRIDE + ks * 32 + quad * 8];

  // Per-wave private S scratch aliases this wave's own 32 rows of the Q tile.
  __bf16* sbuf = &lds_qs[wave * 32 * KSTRIDE];

  f32x4 oacc[2][4];
#pragma unroll
  for (int qs = 0; qs < 2; ++qs)
#pragma unroll
    for (int ds = 0; ds < 4; ++ds)
      oacc[qs][ds] = (f32x4){0.f, 0.f, 0.f, 0.f};

  for (int it = 0; it < 16; ++it) {
    const int kt = (it + kt0) & 15;   // phase-staggered tile index
    BARRIER_LGKM();   // all waves done reading previous K/V LDS tiles

    // ---- write prefetched K (row-major) and V (reg-transposed) as bf16 ----
#pragma unroll
    for (int i = 0; i < 8; ++i) {
      const int r = r0 + (i << 4);
      f32x4 kv = kpre[i];
      bf16x4 pk;
      pk.x = (__bf16)kv.x; pk.y = (__bf16)kv.y;
      pk.z = (__bf16)kv.z; pk.w = (__bf16)kv.w;
      *(bf16x4*)&lds_k[r * KSTRIDE + c] = pk;
    }
#pragma unroll
    for (int j = 0; j < 4; ++j) {       // d-col = c + j
      bf16x8 t;
#pragma unroll
      for (int i = 0; i < 8; ++i)       // k-row = r0*8 + i (consecutive)
        t[i] = (__bf16)vpre[i][j];
      *(bf16x8*)&lds_vt[(c + j) * VSTRIDE + r0 * 8] = t;
    }

    BARRIER_LGKM();   // publish K/V tile

    // ---- issue next tile's loads BEFORE this tile's stores (FIFO vmcnt:
    //      loads older than stores -> LDS-write wait never drains stores) ----
    if (it < 15) {
      const int ktn = (it + 1 + kt0) & 15;
      const float* kp = kbase + (size_t)(ktn * 128) * Dn;
      const float* vp = vbase + (size_t)(ktn * 128) * Dn;
#pragma unroll
      for (int i = 0; i < 8; ++i) {
        kpre[i] = *(const f32x4*)(kp + (r0 + (i << 4)) * Dn + c);
        vpre[i] = *(const f32x4*)(vp + (r0 * 8 + i) * Dn + c);
      }
    }

    // ---- S = K @ Q^T (swapped) fused with mask-fill + f32x4 attn stores.
    //      Plain (cacheable) stores: the wave writes both 64B halves of each
    //      128B sector close together -> L2 merges to full-line writebacks. ----
    f32x4 sacc[2][8];
#pragma unroll
    for (int ns = 0; ns < 8; ++ns) {
      bf16x8 ka0 = *(const bf16x8*)&lds_k[(ns * 16 + l16) * KSTRIDE +      quad * 8];
      bf16x8 ka1 = *(const bf16x8*)&lds_k[(ns * 16 + l16) * KSTRIDE + 32 + quad * 8];
      const i32x4 m4 = *(const i32x4*)&lds_m[kt * 128 + ns * 16 + quad * 4];
#pragma unroll
      for (int qs = 0; qs < 2; ++qs) {
        f32x4 acc = (f32x4){0.f, 0.f, 0.f, 0.f};
        acc = __builtin_amdgcn_mfma_f32_16x16x32_bf16(ka0, qa[qs][0], acc, 0, 0, 0);
        acc = __builtin_amdgcn_mfma_f32_16x16x32_bf16(ka1, qa[qs][1], acc, 0, 0, 0);
        acc.x = m4.x ? acc.x : MASK_FILL;
        acc.y = m4.y ? acc.y : MASK_FILL;
        acc.z = m4.z ? acc.z : MASK_FILL;
        acc.w = m4.w ? acc.w : MASK_FILL;
        sacc[qs][ns] = acc;
        const int row = wave * 32 + qs * 16 + l16;
        *(f32x4*)(attnp + (size_t)row * Sn + kt * 128 + ns * 16 + quad * 4) = acc;
      }
    }

    // ---- O += S @ V, two 64-col halves; S through per-wave LDS scratch,
    //      V via bf16x8 reads from the transposed tile ----
#pragma unroll
    for (int half = 0; half < 2; ++half) {
#pragma unroll
      for (int ns4 = 0; ns4 < 4; ++ns4) {
        const int ns = half * 4 + ns4;
#pragma unroll
        for (int qs = 0; qs < 2; ++qs) {
          f32x4 sv = sacc[qs][ns];
          bf16x4 sb;
          sb.x = (__bf16)sv.x; sb.y = (__bf16)sv.y;
          sb.z = (__bf16)sv.z; sb.w = (__bf16)sv.w;
          *(bf16x4*)&sbuf[(qs * 16 + l16) * KSTRIDE + ns4 * 16 + quad * 4] = sb;
        }
      }
      asm volatile("" ::: "memory");
#pragma unroll
      for (int ks = 0; ks < 2; ++ks) {
        bf16x8 sb0 = *(const bf16x8*)&sbuf[(     l16) * KSTRIDE + ks * 32 + quad * 8];
        bf16x8 sb1 = *(const bf16x8*)&sbuf[(16 + l16) * KSTRIDE + ks * 32 + quad * 8];
#pragma unroll
        for (int ds = 0; ds < 4; ++ds) {
          bf16x8 va = *(const bf16x8*)&lds_vt[(ds * 16 + l16) * VSTRIDE + half * 64 + ks * 32 + quad * 8];
          // swapped: D[m = d-offset][n = q-row] -> epilogue stores are f32x4
          oacc[0][ds] = __builtin_amdgcn_mfma_f32_16x16x32_bf16(va, sb0, oacc[0][ds], 0, 0, 0);
          oacc[1][ds] = __builtin_amdgcn_mfma_f32_16x16x32_bf16(va, sb1, oacc[1][ds], 0, 0, 0);
        }
      }
      asm volatile("" ::: "memory");  // keep next half's sbuf writes after these reads
    }
  }

  // ---- epilogue: vectorized O stores (lane holds 4 consecutive d) ----
  float* op = outg + hbase + (size_t)qt * 128 * Dn;
#pragma unroll
  for (int qs = 0; qs < 2; ++qs)
#pragma unroll
    for (int ds = 0; ds < 4; ++ds) {
      const int row = wave * 32 + qs * 16 + l16;
      __builtin_nontemporal_store(oacc[qs][ds],
          (f32x4*)(op + (size_t)row * Dn + ds * 16 + quad * 4));
    }
}

extern "C" void kernel_launch(void* const* d_in, const int* in_sizes, int n_in,
                              void* d_out, int out_size, void* d_ws, size_t ws_size,
                              hipStream_t stream) {
  const float* q    = (const float*)d_in[0];
  const float* k    = (const float*)d_in[1];
  const float* v    = (const float*)d_in[2];
  const int*   mask = (const int*)d_in[3];
  float* out  = (float*)d_out;
  float* attn = out + (size_t)Bn * Hn * Sn * Dn;   // outputs concatenated: (output, attn)

  dim3 grid(Sn / 128, Bn * Hn);
  attn_fused<<<grid, 256, 0, stream>>>(q, k, v, mask, out, attn);
}